// Round 17
// baseline (294.525 us; speedup 1.0000x reference)
//
#include <hip/hip_runtime.h>
#include <hip/hip_bf16.h>
#include <math.h>

#define BB 32
#define TTOT 1024
#define KK 16
#define DD 80
#define PP 64

// workspace layout (float offsets)
#define WS_DCONST 128      // 512
#define WS_CVEC   1024     // 512*80 -> 41984
#define WS_PART2  41984    // 2048 -> 44032
#define WS_PART3L 44032    // 1600 -> 45632
#define WS_PART3M 45632    // 64 -> 45696
#define WS_DONE   45696    // 1 int ticket (zeroed by k_prep each call)
#define WS_GAMT   46080    // gamma^T fp32 [32][16][1024] -> 570368
#define WS_XBF16  570368   // X frag-major bf16 -> 2,143,232
#define WS_MINVB  2143232  // Minv frag-major bf16 -> 4,109,312 (16.4 MB)

typedef short bf16x8 __attribute__((ext_vector_type(8)));
typedef float f32x4 __attribute__((ext_vector_type(4)));

__device__ __forceinline__ float wave_sum(float v) {
#pragma unroll
  for (int o = 32; o > 0; o >>= 1) v += __shfl_down(v, o);
  return v;
}

__device__ __forceinline__ unsigned short f2bf(float f) {
  __hip_bfloat16 h = __float2bfloat16(f);
  return *reinterpret_cast<unsigned short*>(&h);
}

__device__ __forceinline__ bf16x8 pack8(float4 a, float4 b) {
  bf16x8 r;
  r[0] = (short)f2bf(a.x); r[1] = (short)f2bf(a.y);
  r[2] = (short)f2bf(a.z); r[3] = (short)f2bf(a.w);
  r[4] = (short)f2bf(b.x); r[5] = (short)f2bf(b.y);
  r[6] = (short)f2bf(b.z); r[7] = (short)f2bf(b.w);
  return r;
}

struct SmKx { float Lx[2][16][84]; };
struct SmKg { float tile[256][17]; };
struct SmK1 {
  float ys[DD * 81 + 64];
  float dinv[DD * 20];
  float Ls5[5][16][17];
  float lgd[DD];
  float rt[4][16 * 17];
};

// ---- PREP: k1_inv (blocks 0-511, HEAVIEST -> dispatched first) +
//            kx_cast (512-1535, 2 groups each) + kg_t (1536-1663).
__global__ __launch_bounds__(256, 1) void k_prep(const float* __restrict__ x,
                                                 const float* __restrict__ gamma,
                                                 const float* __restrict__ L_subj,
                                                 const float* __restrict__ mu_subj,
                                                 const int* __restrict__ sids,
                                                 float* __restrict__ ws) {
  __shared__ union { SmKx kx; SmKg kg; SmK1 k1; } sm;
  const int bid = blockIdx.x;
  const int tid = threadIdx.x;

  if (bid < 512) {
    // ---- role K1: triangular inverse via MFMA block recursion
    if (bid == 0 && tid == 0) reinterpret_cast<int*>(ws + WS_DONE)[0] = 0;
    const int k = bid & 15, b = bid >> 4;
    const int p = sids[b];
    const float* Lg = L_subj + ((size_t)(p * KK + k)) * DD * DD;
    const float* mug = mu_subj + (size_t)(p * KK + k) * DD;
    const int bk = b * KK + k;

    const int w = tid >> 6, l = tid & 63;
    const int lr = l & 15, lg = l >> 4;

    for (int i2 = tid; i2 < 5 * 256; i2 += 256) {
      int blk = i2 >> 8, ii = (i2 >> 4) & 15, mm = i2 & 15;
      sm.k1.Ls5[blk][ii][mm] = Lg[(blk * 16 + ii) * DD + blk * 16 + mm];
    }
    for (int i2 = tid; i2 < DD * 81 + 64; i2 += 256) sm.k1.ys[i2] = 0.f;
    __syncthreads();

    // Phase 1: invert diagonal 16x16 blocks from LDS (tid<80)
    if (tid < DD) {
      const int ci5 = tid >> 4, jj = tid & 15;
      float rd[16];
#pragma unroll
      for (int ii = 0; ii < 16; ++ii) rd[ii] = 1.0f / sm.k1.Ls5[ci5][ii][ii];
      float yc[16];
#pragma unroll
      for (int ii = 0; ii < 16; ++ii) {
        float v = (ii == jj) ? 1.0f : 0.0f;
#pragma unroll
        for (int mm = 0; mm < 16; ++mm)
          if (mm < ii) v = fmaf(-sm.k1.Ls5[ci5][ii][mm], yc[mm], v);
        yc[ii] = v * rd[ii];
      }
#pragma unroll
      for (int ii = 0; ii < 16; ++ii) sm.k1.dinv[(ci5 * 16 + ii) * 20 + jj] = yc[ii];
      sm.k1.lgd[tid] = logf(sm.k1.Ls5[ci5][jj][jj]);
    }
    __syncthreads();

    // Phase 2: 4-wave column ownership (w0:{0} w1:{1} w2:{2} w3:{3,4}),
    // lower-triangular tiles only, diagonal = Dinv copy. No barriers inside.
    float* rtw = sm.k1.rt[w];
    for (int nt = w; nt < 5; nt += (w == 3) ? 1 : 5) {
      const int col = nt * 16 + lr;
      if (lg == 0) {
#pragma unroll
        for (int ii = 0; ii < 16; ++ii)
          sm.k1.ys[(nt * 16 + ii) * 81 + col] = sm.k1.dinv[(nt * 16 + ii) * 20 + lr];
      }
      for (int ci = nt + 1; ci < 5; ++ci) {
        const int r0 = ci * 16;
        const int ktot = ci * 16;
        const int nch = (ci + 1) >> 1;

        bf16x8 aL0 = {}, aL1 = {};
        if (nch > 0 && (lg * 8) < ktot) {
          const float* src = &Lg[(r0 + lr) * DD + lg * 8];
          aL0 = pack8(*reinterpret_cast<const float4*>(src),
                      *reinterpret_cast<const float4*>(src + 4));
        }
        if (nch > 1 && (32 + lg * 8) < ktot) {
          const float* src = &Lg[(r0 + lr) * DD + 32 + lg * 8];
          aL1 = pack8(*reinterpret_cast<const float4*>(src),
                      *reinterpret_cast<const float4*>(src + 4));
        }
        bf16x8 aD = {};
        if (lg < 2) {
          const float* src = &sm.k1.dinv[(r0 + lr) * 20 + lg * 8];
          aD = pack8(*reinterpret_cast<const float4*>(src),
                     *reinterpret_cast<const float4*>(src + 4));
        }

        f32x4 S = {};
        if (nch > 0) {
          bf16x8 b0 = {};
          if ((lg * 8) < ktot) {
            const int kb = lg * 8;
#pragma unroll
            for (int jj = 0; jj < 8; ++jj)
              b0[jj] = (short)f2bf(sm.k1.ys[(kb + jj) * 81 + col]);
          }
          S = __builtin_amdgcn_mfma_f32_16x16x32_bf16(aL0, b0, S, 0, 0, 0);
        }
        if (nch > 1) {
          bf16x8 b1 = {};
          if ((32 + lg * 8) < ktot) {
            const int kb = 32 + lg * 8;
#pragma unroll
            for (int jj = 0; jj < 8; ++jj)
              b1[jj] = (short)f2bf(sm.k1.ys[(kb + jj) * 81 + col]);
          }
          S = __builtin_amdgcn_mfma_f32_16x16x32_bf16(aL1, b1, S, 0, 0, 0);
        }
#pragma unroll
        for (int r = 0; r < 4; ++r) rtw[(lg * 4 + r) * 17 + lr] = -S[r];
        bf16x8 bR = {};
        if (lg < 2) {
#pragma unroll
          for (int jj = 0; jj < 8; ++jj)
            bR[jj] = (short)f2bf(rtw[(lg * 8 + jj) * 17 + lr]);
        }
        f32x4 Y = {};
        Y = __builtin_amdgcn_mfma_f32_16x16x32_bf16(aD, bR, Y, 0, 0, 0);
#pragma unroll
        for (int r = 0; r < 4; ++r) sm.k1.ys[(r0 + lg * 4 + r) * 81 + col] = Y[r];
      }
    }
    __syncthreads();

    // Minv write in A-fragment-major layout (zeros in K-pad slots)
    __hip_bfloat16* Mf = (__hip_bfloat16*)(ws + WS_MINVB) + (size_t)bk * 7680;
    for (int s = tid; s < 960; s += 256) {
      int mtc = s >> 6, l2 = s & 63;
      int row = (mtc / 3) * 16 + (l2 & 15);
      int col0 = (mtc % 3) * 32 + (l2 >> 4) * 8;
      bf16x8 v = {};
      if (col0 < DD) {
#pragma unroll
        for (int jj = 0; jj < 8; ++jj) v[jj] = (short)f2bf(sm.k1.ys[row * 81 + col0 + jj]);
      }
      *reinterpret_cast<bf16x8*>(Mf + s * 8) = v;
    }

    if (tid < DD) {
      int i = tid;
      float ci = 0.f;
#pragma unroll 8
      for (int jj = 0; jj < DD; ++jj) ci = fmaf(sm.k1.ys[i * 81 + jj], mug[jj], ci);
      ws[WS_CVEC + bk * DD + i] = ci;
    }
    if (tid == 0) {
      float s = 0.f;
      for (int i = 0; i < DD; ++i) s += sm.k1.lgd[i];
      ws[WS_DCONST + bk] = (float)(0.5 * 80.0 * 1.8378770664093453) + s;
    }
    return;
  }

  if (bid < 1536) {
    // ---- role KX: x -> bf16 B-fragment-major; half-block per 16-t group
    const int h = tid >> 7, t = tid & 127;
    const int g = (bid - 512) * 2 + h;
    float(&Lx)[16][84] = sm.kx.Lx[h];
    const float* src = x + (size_t)g * 1280;
    for (int i2 = t; i2 < 320; i2 += 128) {
      float4 v = reinterpret_cast<const float4*>(src)[i2];
      int row = i2 / 20, c4 = (i2 % 20) * 4;
      *reinterpret_cast<float4*>(&Lx[row][c4]) = v;
    }
    __syncthreads();
    __hip_bfloat16* Xf = (__hip_bfloat16*)(ws + WS_XBF16) + (size_t)g * 1536;
    for (int s = t; s < 192; s += 128) {
      int c = s >> 6, l = s & 63, lg2 = (l >> 4), lr2 = l & 15;
      int col0 = c * 32 + lg2 * 8;
      bf16x8 v = {};
      if (col0 < DD) {
#pragma unroll
        for (int jj = 0; jj < 8; ++jj) v[jj] = (short)f2bf(Lx[lr2][col0 + jj]);
      }
      *reinterpret_cast<bf16x8*>(Xf + s * 8) = v;
    }
    return;
  }

  // ---- role KG: gamma [b][t][k] -> [b][k][t]
  const int idx0 = bid - 1536;
  const int tc = idx0 & 3, b = idx0 >> 2;
  const float* src = gamma + ((size_t)b * TTOT + tc * 256) * KK;
#pragma unroll
  for (int q = 0; q < 16; ++q) {
    int i2 = q * 256 + tid;
    sm.kg.tile[i2 >> 4][i2 & 15] = src[i2];
  }
  __syncthreads();
  float* dst = ws + WS_GAMT + (size_t)b * KK * TTOT;
#pragma unroll
  for (int q = 0; q < 16; ++q) {
    int i2 = q * 256 + tid;
    int kk = i2 >> 8, tl = i2 & 255;
    dst[kk * TTOT + tc * 256 + tl] = sm.kg.tile[tl][kk];
  }
}

// ---- MAIN: k2_mfma (0-2047) + k3 reg (2048-3711) + last-block final reduce
__global__ __launch_bounds__(256) void k_main(const float* __restrict__ ws_ro,
                                              const float* __restrict__ L_subj,
                                              const float* __restrict__ L_pop,
                                              const float* __restrict__ mu_subj,
                                              const float* __restrict__ mu_pop,
                                              const int* __restrict__ sids,
                                              float* __restrict__ ws,
                                              float* __restrict__ out) {
  __shared__ float red[4];
  __shared__ int amlast;
  const int bid = blockIdx.x;
  const int tid = threadIdx.x;

  if (bid < 2048) {
    // ---- role K2
    const int k = bid & 15, tt = (bid >> 4) & 3, b = bid >> 6;
    const int w = tid >> 6, l = tid & 63;
    const int lg = l >> 4, lr = l & 15;
    const int bk = b * KK + k;

    const __hip_bfloat16* Mf = (const __hip_bfloat16*)(ws_ro + WS_MINVB) + (size_t)bk * 7680;
    const __hip_bfloat16* Xf = (const __hip_bfloat16*)(ws_ro + WS_XBF16);
    const float* gamt = ws_ro + WS_GAMT + ((size_t)b * KK + k) * TTOT;
    const float* cc = ws_ro + WS_CVEC + bk * DD;
    const float dconst = ws_ro[WS_DCONST + bk];

    const int t0 = tt * 256 + w * 64;
    const int tg0 = tt * 16 + w * 4;

    f32x4 accf[5][4] = {};
#pragma unroll
    for (int c = 0; c < 3; ++c) {
      bf16x8 af[5], bf[4];
#pragma unroll
      for (int mt = 0; mt < 5; ++mt)
        af[mt] = *(const bf16x8*)(Mf + ((mt * 3 + c) * 64 + l) * 8);
#pragma unroll
      for (int nf = 0; nf < 4; ++nf)
        bf[nf] = *(const bf16x8*)(Xf + ((size_t)(b * 64 + tg0 + nf) * 192 + c * 64 + l) * 8);
#pragma unroll
      for (int mt = 0; mt < 5; ++mt)
#pragma unroll
        for (int nf = 0; nf < 4; ++nf)
          accf[mt][nf] = __builtin_amdgcn_mfma_f32_16x16x32_bf16(af[mt], bf[nf], accf[mt][nf], 0, 0, 0);
    }

    float c_r[5][4];
#pragma unroll
    for (int mt = 0; mt < 5; ++mt)
#pragma unroll
      for (int r = 0; r < 4; ++r)
        c_r[mt][r] = cc[mt * 16 + lg * 4 + r];

    float v = 0.f;
#pragma unroll
    for (int nf = 0; nf < 4; ++nf) {
      float s = 0.f;
#pragma unroll
      for (int mt = 0; mt < 5; ++mt)
#pragma unroll
        for (int r = 0; r < 4; ++r) {
          float z = accf[mt][nf][r] - c_r[mt][r];
          s = fmaf(z, z, s);
        }
      s += __shfl_xor(s, 16);
      s += __shfl_xor(s, 32);
      float g = 0.f;
      int t = t0 + nf * 16 + lr;
      if (l < 16) g = gamt[t];
      v = fmaf(g, dconst + 0.5f * s, v);
    }
    v = wave_sum(v);
    if (l == 0) red[w] = v;
    __syncthreads();
    if (tid == 0)
      ws[WS_PART2 + (b * 4 + tt) * KK + k] = red[0] + red[1] + red[2] + red[3];
  } else {
    // ---- role K3: L reg (chunk 0-24) + mu reg (chunk 25)
    const int idx = bid - 2048;
    const int p = idx / 26, chunk = idx - p * 26;
    int found = 0;
    for (int b2 = 0; b2 < BB; ++b2) found |= (sids[b2] == p) ? 1 : 0;
    float* outp = (chunk < 25) ? &ws[WS_PART3L + p * 25 + chunk] : &ws[WS_PART3M + p];
    if (!found) {
      if (tid == 0) *outp = 0.f;
    } else {
      float s = 0.f;
      if (chunk < 25) {
        const float4* a4 = reinterpret_cast<const float4*>(L_subj) + (size_t)p * (KK * DD * DD / 4);
        const float4* b4 = reinterpret_cast<const float4*>(L_pop);
#pragma unroll
        for (int q = 0; q < 4; ++q) {
          int o = chunk * 1024 + q * 256 + tid;
          float4 a = a4[o], bb = b4[o];
          float d0 = a.x - bb.x, d1 = a.y - bb.y, d2 = a.z - bb.z, d3 = a.w - bb.w;
          s += d0 * d0 + d1 * d1 + d2 * d2 + d3 * d3;
        }
      } else {
        const float4* a4 = reinterpret_cast<const float4*>(mu_subj) + (size_t)p * (KK * DD / 4);
        const float4* b4 = reinterpret_cast<const float4*>(mu_pop);
        for (int o = tid; o < 320; o += 256) {
          float4 a = a4[o], bb = b4[o];
          float d0 = a.x - bb.x, d1 = a.y - bb.y, d2 = a.z - bb.z, d3 = a.w - bb.w;
          s += d0 * d0 + d1 * d1 + d2 * d2 + d3 * d3;
        }
      }
      s = wave_sum(s);
      if ((tid & 63) == 0) red[tid >> 6] = s;
      __syncthreads();
      if (tid == 0) *outp = red[0] + red[1] + red[2] + red[3];
    }
  }

  // ---- completion ticket: last of 3712 blocks runs the final reduction
  __threadfence();
  if (tid == 0) {
    int t = atomicAdd(reinterpret_cast<int*>(ws + WS_DONE), 1);
    amlast = (t == 3711) ? 1 : 0;
  }
  __syncthreads();
  if (!amlast) return;
  __threadfence();

  __shared__ float nuniq;
  if (tid < 64) {
    int found = 0;
    for (int b2 = 0; b2 < BB; ++b2) found |= (sids[b2] == tid) ? 1 : 0;
    unsigned long long bal = __ballot(found != 0);
    if (tid == 0) nuniq = (float)__popcll(bal);
  }
  __syncthreads();
  float scale = nuniq / 64.0f;

  float a = 0.f;
  for (int i = tid; i < 2048; i += 256) a += ws[WS_PART2 + i];
  float lr2 = 0.f;
  for (int i = tid; i < 1600; i += 256) lr2 += ws[WS_PART3L + i];
  float mr = 0.f;
  if (tid < 64) mr = ws[WS_PART3M + tid];

  float v = a / 32768.0f + scale * 0.05f * (lr2 + mr);
  v = wave_sum(v);
  if ((tid & 63) == 0) red[tid >> 6] = v;
  __syncthreads();
  if (tid == 0) out[0] = red[0] + red[1] + red[2] + red[3];
}

extern "C" void kernel_launch(void* const* d_in, const int* in_sizes, int n_in,
                              void* d_out, int out_size, void* d_ws, size_t ws_size,
                              hipStream_t stream) {
  const float* x       = (const float*)d_in[0];
  const float* mu_pop  = (const float*)d_in[1];
  const float* L_pop   = (const float*)d_in[2];
  const float* mu_subj = (const float*)d_in[3];
  const float* L_subj  = (const float*)d_in[4];
  const float* gamma   = (const float*)d_in[5];
  const int*   sids    = (const int*)d_in[6];
  float* out = (float*)d_out;
  float* ws  = (float*)d_ws;

  hipLaunchKernelGGL(k_prep, dim3(1664), dim3(256), 0, stream,
                     x, gamma, L_subj, mu_subj, sids, ws);
  hipLaunchKernelGGL(k_main, dim3(3712), dim3(256), 0, stream,
                     ws, L_subj, L_pop, mu_subj, mu_pop, sids, ws, out);
}

// Round 18
// 46.604 us; speedup vs baseline: 6.3197x; 6.3197x over previous
//
#include <hip/hip_runtime.h>
#include <hip/hip_bf16.h>
#include <math.h>

#define BB 32
#define TTOT 1024
#define KK 16
#define DD 80
#define PP 64

// workspace layout (float offsets)
#define WS_DCONST 128      // 512
#define WS_CVEC   1024     // 512*80 -> 41984
#define WS_PART2  41984    // 2048 -> 44032
#define WS_PART3L 44032    // 1600 -> 45632
#define WS_PART3M 45632    // 64 -> 45696
#define WS_GAMT   46080    // gamma^T fp32 [32][16][1024] -> 570368
#define WS_XBF16  570368   // X frag-major bf16 -> 2,143,232
#define WS_MINVB  2143232  // Minv frag-major bf16 -> 4,109,312 (16.4 MB)

typedef short bf16x8 __attribute__((ext_vector_type(8)));
typedef float f32x4 __attribute__((ext_vector_type(4)));

__device__ __forceinline__ float wave_sum(float v) {
#pragma unroll
  for (int o = 32; o > 0; o >>= 1) v += __shfl_down(v, o);
  return v;
}

__device__ __forceinline__ unsigned short f2bf(float f) {
  __hip_bfloat16 h = __float2bfloat16(f);
  return *reinterpret_cast<unsigned short*>(&h);
}

__device__ __forceinline__ bf16x8 pack8(float4 a, float4 b) {
  bf16x8 r;
  r[0] = (short)f2bf(a.x); r[1] = (short)f2bf(a.y);
  r[2] = (short)f2bf(a.z); r[3] = (short)f2bf(a.w);
  r[4] = (short)f2bf(b.x); r[5] = (short)f2bf(b.y);
  r[6] = (short)f2bf(b.z); r[7] = (short)f2bf(b.w);
  return r;
}

struct SmKx { float Lx[2][16][84]; };
struct SmKg { float tile[256][17]; };
struct SmK1 {
  float ys[DD * 81 + 64];
  float dinv[DD * 20];
  float Ls5[5][16][17];
  float lgd[DD];
  float rt[4][16 * 17];
};

// ---- PREP: k1_inv (blocks 0-511, HEAVIEST -> dispatched first) +
//            kx_cast (512-1535, 2 groups each) + kg_t (1536-1663).
// R17 lesson: completion-ticket (threadfence+atomic per block) cost 245us —
// reverted. Separate 1-block k4 launch is cheap by comparison.
__global__ __launch_bounds__(256, 1) void k_prep(const float* __restrict__ x,
                                                 const float* __restrict__ gamma,
                                                 const float* __restrict__ L_subj,
                                                 const float* __restrict__ mu_subj,
                                                 const int* __restrict__ sids,
                                                 float* __restrict__ ws) {
  __shared__ union { SmKx kx; SmKg kg; SmK1 k1; } sm;
  const int bid = blockIdx.x;
  const int tid = threadIdx.x;

  if (bid < 512) {
    // ---- role K1: triangular inverse via MFMA block recursion
    const int k = bid & 15, b = bid >> 4;
    const int p = sids[b];
    const float* Lg = L_subj + ((size_t)(p * KK + k)) * DD * DD;
    const float* mug = mu_subj + (size_t)(p * KK + k) * DD;
    const int bk = b * KK + k;

    const int w = tid >> 6, l = tid & 63;
    const int lr = l & 15, lg = l >> 4;

    for (int i2 = tid; i2 < 5 * 256; i2 += 256) {
      int blk = i2 >> 8, ii = (i2 >> 4) & 15, mm = i2 & 15;
      sm.k1.Ls5[blk][ii][mm] = Lg[(blk * 16 + ii) * DD + blk * 16 + mm];
    }
    for (int i2 = tid; i2 < DD * 81 + 64; i2 += 256) sm.k1.ys[i2] = 0.f;
    __syncthreads();

    // Phase 1: invert diagonal 16x16 blocks from LDS (tid<80)
    if (tid < DD) {
      const int ci5 = tid >> 4, jj = tid & 15;
      float rd[16];
#pragma unroll
      for (int ii = 0; ii < 16; ++ii) rd[ii] = 1.0f / sm.k1.Ls5[ci5][ii][ii];
      float yc[16];
#pragma unroll
      for (int ii = 0; ii < 16; ++ii) {
        float v = (ii == jj) ? 1.0f : 0.0f;
#pragma unroll
        for (int mm = 0; mm < 16; ++mm)
          if (mm < ii) v = fmaf(-sm.k1.Ls5[ci5][ii][mm], yc[mm], v);
        yc[ii] = v * rd[ii];
      }
#pragma unroll
      for (int ii = 0; ii < 16; ++ii) sm.k1.dinv[(ci5 * 16 + ii) * 20 + jj] = yc[ii];
      sm.k1.lgd[tid] = logf(sm.k1.Ls5[ci5][jj][jj]);
    }
    __syncthreads();

    // Phase 2: 4-wave column ownership (w0:{0} w1:{1} w2:{2} w3:{3,4}),
    // lower-triangular tiles only, diagonal = Dinv copy. No barriers inside.
    float* rtw = sm.k1.rt[w];
    for (int nt = w; nt < 5; nt += (w == 3) ? 1 : 5) {
      const int col = nt * 16 + lr;
      if (lg == 0) {
#pragma unroll
        for (int ii = 0; ii < 16; ++ii)
          sm.k1.ys[(nt * 16 + ii) * 81 + col] = sm.k1.dinv[(nt * 16 + ii) * 20 + lr];
      }
      for (int ci = nt + 1; ci < 5; ++ci) {
        const int r0 = ci * 16;
        const int ktot = ci * 16;
        const int nch = (ci + 1) >> 1;

        bf16x8 aL0 = {}, aL1 = {};
        if (nch > 0 && (lg * 8) < ktot) {
          const float* src = &Lg[(r0 + lr) * DD + lg * 8];
          aL0 = pack8(*reinterpret_cast<const float4*>(src),
                      *reinterpret_cast<const float4*>(src + 4));
        }
        if (nch > 1 && (32 + lg * 8) < ktot) {
          const float* src = &Lg[(r0 + lr) * DD + 32 + lg * 8];
          aL1 = pack8(*reinterpret_cast<const float4*>(src),
                      *reinterpret_cast<const float4*>(src + 4));
        }
        bf16x8 aD = {};
        if (lg < 2) {
          const float* src = &sm.k1.dinv[(r0 + lr) * 20 + lg * 8];
          aD = pack8(*reinterpret_cast<const float4*>(src),
                     *reinterpret_cast<const float4*>(src + 4));
        }

        f32x4 S = {};
        if (nch > 0) {
          bf16x8 b0 = {};
          if ((lg * 8) < ktot) {
            const int kb = lg * 8;
#pragma unroll
            for (int jj = 0; jj < 8; ++jj)
              b0[jj] = (short)f2bf(sm.k1.ys[(kb + jj) * 81 + col]);
          }
          S = __builtin_amdgcn_mfma_f32_16x16x32_bf16(aL0, b0, S, 0, 0, 0);
        }
        if (nch > 1) {
          bf16x8 b1 = {};
          if ((32 + lg * 8) < ktot) {
            const int kb = 32 + lg * 8;
#pragma unroll
            for (int jj = 0; jj < 8; ++jj)
              b1[jj] = (short)f2bf(sm.k1.ys[(kb + jj) * 81 + col]);
          }
          S = __builtin_amdgcn_mfma_f32_16x16x32_bf16(aL1, b1, S, 0, 0, 0);
        }
#pragma unroll
        for (int r = 0; r < 4; ++r) rtw[(lg * 4 + r) * 17 + lr] = -S[r];
        bf16x8 bR = {};
        if (lg < 2) {
#pragma unroll
          for (int jj = 0; jj < 8; ++jj)
            bR[jj] = (short)f2bf(rtw[(lg * 8 + jj) * 17 + lr]);
        }
        f32x4 Y = {};
        Y = __builtin_amdgcn_mfma_f32_16x16x32_bf16(aD, bR, Y, 0, 0, 0);
#pragma unroll
        for (int r = 0; r < 4; ++r) sm.k1.ys[(r0 + lg * 4 + r) * 81 + col] = Y[r];
      }
    }
    __syncthreads();

    // Minv write in A-fragment-major layout (zeros in K-pad slots)
    __hip_bfloat16* Mf = (__hip_bfloat16*)(ws + WS_MINVB) + (size_t)bk * 7680;
    for (int s = tid; s < 960; s += 256) {
      int mtc = s >> 6, l2 = s & 63;
      int row = (mtc / 3) * 16 + (l2 & 15);
      int col0 = (mtc % 3) * 32 + (l2 >> 4) * 8;
      bf16x8 v = {};
      if (col0 < DD) {
#pragma unroll
        for (int jj = 0; jj < 8; ++jj) v[jj] = (short)f2bf(sm.k1.ys[row * 81 + col0 + jj]);
      }
      *reinterpret_cast<bf16x8*>(Mf + s * 8) = v;
    }

    if (tid < DD) {
      int i = tid;
      float ci = 0.f;
#pragma unroll 8
      for (int jj = 0; jj < DD; ++jj) ci = fmaf(sm.k1.ys[i * 81 + jj], mug[jj], ci);
      ws[WS_CVEC + bk * DD + i] = ci;
    }
    if (tid == 0) {
      float s = 0.f;
      for (int i = 0; i < DD; ++i) s += sm.k1.lgd[i];
      ws[WS_DCONST + bk] = (float)(0.5 * 80.0 * 1.8378770664093453) + s;
    }
    return;
  }

  if (bid < 1536) {
    // ---- role KX: x -> bf16 B-fragment-major; half-block per 16-t group
    const int h = tid >> 7, t = tid & 127;
    const int g = (bid - 512) * 2 + h;
    float(&Lx)[16][84] = sm.kx.Lx[h];
    const float* src = x + (size_t)g * 1280;
    for (int i2 = t; i2 < 320; i2 += 128) {
      float4 v = reinterpret_cast<const float4*>(src)[i2];
      int row = i2 / 20, c4 = (i2 % 20) * 4;
      *reinterpret_cast<float4*>(&Lx[row][c4]) = v;
    }
    __syncthreads();
    __hip_bfloat16* Xf = (__hip_bfloat16*)(ws + WS_XBF16) + (size_t)g * 1536;
    for (int s = t; s < 192; s += 128) {
      int c = s >> 6, l = s & 63, lg2 = (l >> 4), lr2 = l & 15;
      int col0 = c * 32 + lg2 * 8;
      bf16x8 v = {};
      if (col0 < DD) {
#pragma unroll
        for (int jj = 0; jj < 8; ++jj) v[jj] = (short)f2bf(Lx[lr2][col0 + jj]);
      }
      *reinterpret_cast<bf16x8*>(Xf + s * 8) = v;
    }
    return;
  }

  // ---- role KG: gamma [b][t][k] -> [b][k][t]
  const int idx0 = bid - 1536;
  const int tc = idx0 & 3, b = idx0 >> 2;
  const float* src = gamma + ((size_t)b * TTOT + tc * 256) * KK;
#pragma unroll
  for (int q = 0; q < 16; ++q) {
    int i2 = q * 256 + tid;
    sm.kg.tile[i2 >> 4][i2 & 15] = src[i2];
  }
  __syncthreads();
  float* dst = ws + WS_GAMT + (size_t)b * KK * TTOT;
#pragma unroll
  for (int q = 0; q < 16; ++q) {
    int i2 = q * 256 + tid;
    int kk = i2 >> 8, tl = i2 & 255;
    dst[kk * TTOT + tc * 256 + tl] = sm.kg.tile[tl][kk];
  }
}

// ---- MAIN: k2_mfma (0-2047) + k3 regularizers (2048-3711) ----
__global__ __launch_bounds__(256) void k_main(const float* __restrict__ ws_ro,
                                              const float* __restrict__ L_subj,
                                              const float* __restrict__ L_pop,
                                              const float* __restrict__ mu_subj,
                                              const float* __restrict__ mu_pop,
                                              const int* __restrict__ sids,
                                              float* __restrict__ ws) {
  __shared__ float red[4];
  const int bid = blockIdx.x;
  const int tid = threadIdx.x;

  if (bid < 2048) {
    // ---- role K2
    const int k = bid & 15, tt = (bid >> 4) & 3, b = bid >> 6;
    const int w = tid >> 6, l = tid & 63;
    const int lg = l >> 4, lr = l & 15;
    const int bk = b * KK + k;

    const __hip_bfloat16* Mf = (const __hip_bfloat16*)(ws_ro + WS_MINVB) + (size_t)bk * 7680;
    const __hip_bfloat16* Xf = (const __hip_bfloat16*)(ws_ro + WS_XBF16);
    const float* gamt = ws_ro + WS_GAMT + ((size_t)b * KK + k) * TTOT;
    const float* cc = ws_ro + WS_CVEC + bk * DD;
    const float dconst = ws_ro[WS_DCONST + bk];

    const int t0 = tt * 256 + w * 64;
    const int tg0 = tt * 16 + w * 4;

    f32x4 accf[5][4] = {};
#pragma unroll
    for (int c = 0; c < 3; ++c) {
      bf16x8 af[5], bf[4];
#pragma unroll
      for (int mt = 0; mt < 5; ++mt)
        af[mt] = *(const bf16x8*)(Mf + ((mt * 3 + c) * 64 + l) * 8);
#pragma unroll
      for (int nf = 0; nf < 4; ++nf)
        bf[nf] = *(const bf16x8*)(Xf + ((size_t)(b * 64 + tg0 + nf) * 192 + c * 64 + l) * 8);
#pragma unroll
      for (int mt = 0; mt < 5; ++mt)
#pragma unroll
        for (int nf = 0; nf < 4; ++nf)
          accf[mt][nf] = __builtin_amdgcn_mfma_f32_16x16x32_bf16(af[mt], bf[nf], accf[mt][nf], 0, 0, 0);
    }

    float c_r[5][4];
#pragma unroll
    for (int mt = 0; mt < 5; ++mt)
#pragma unroll
      for (int r = 0; r < 4; ++r)
        c_r[mt][r] = cc[mt * 16 + lg * 4 + r];

    float v = 0.f;
#pragma unroll
    for (int nf = 0; nf < 4; ++nf) {
      float s = 0.f;
#pragma unroll
      for (int mt = 0; mt < 5; ++mt)
#pragma unroll
        for (int r = 0; r < 4; ++r) {
          float z = accf[mt][nf][r] - c_r[mt][r];
          s = fmaf(z, z, s);
        }
      s += __shfl_xor(s, 16);
      s += __shfl_xor(s, 32);
      float g = 0.f;
      int t = t0 + nf * 16 + lr;
      if (l < 16) g = gamt[t];
      v = fmaf(g, dconst + 0.5f * s, v);
    }
    v = wave_sum(v);
    if (l == 0) red[w] = v;
    __syncthreads();
    if (tid == 0)
      ws[WS_PART2 + (b * 4 + tt) * KK + k] = red[0] + red[1] + red[2] + red[3];
    return;
  }

  // ---- role K3: L reg (chunk 0-24) + mu reg (chunk 25)
  const int idx = bid - 2048;
  const int p = idx / 26, chunk = idx - p * 26;
  int found = 0;
  for (int b2 = 0; b2 < BB; ++b2) found |= (sids[b2] == p) ? 1 : 0;
  float* outp = (chunk < 25) ? &ws[WS_PART3L + p * 25 + chunk] : &ws[WS_PART3M + p];
  if (!found) {
    if (tid == 0) *outp = 0.f;
    return;
  }
  float s = 0.f;
  if (chunk < 25) {
    const float4* a4 = reinterpret_cast<const float4*>(L_subj) + (size_t)p * (KK * DD * DD / 4);
    const float4* b4 = reinterpret_cast<const float4*>(L_pop);
#pragma unroll
    for (int q = 0; q < 4; ++q) {
      int o = chunk * 1024 + q * 256 + tid;
      float4 a = a4[o], bb = b4[o];
      float d0 = a.x - bb.x, d1 = a.y - bb.y, d2 = a.z - bb.z, d3 = a.w - bb.w;
      s += d0 * d0 + d1 * d1 + d2 * d2 + d3 * d3;
    }
  } else {
    const float4* a4 = reinterpret_cast<const float4*>(mu_subj) + (size_t)p * (KK * DD / 4);
    const float4* b4 = reinterpret_cast<const float4*>(mu_pop);
    for (int o = tid; o < 320; o += 256) {
      float4 a = a4[o], bb = b4[o];
      float d0 = a.x - bb.x, d1 = a.y - bb.y, d2 = a.z - bb.z, d3 = a.w - bb.w;
      s += d0 * d0 + d1 * d1 + d2 * d2 + d3 * d3;
    }
  }
  s = wave_sum(s);
  if ((tid & 63) == 0) red[tid >> 6] = s;
  __syncthreads();
  if (tid == 0) *outp = red[0] + red[1] + red[2] + red[3];
}

// ---- K4: reduce all partials, compute n_unique, combine ----
__global__ __launch_bounds__(256) void k4_final(const int* __restrict__ sids,
                                                const float* __restrict__ ws,
                                                float* __restrict__ out) {
  int tid = threadIdx.x;
  __shared__ float nuniq;
  if (tid < 64) {
    int found = 0;
    for (int b2 = 0; b2 < BB; ++b2) found |= (sids[b2] == tid) ? 1 : 0;
    unsigned long long bal = __ballot(found != 0);
    if (tid == 0) nuniq = (float)__popcll(bal);
  }
  __syncthreads();
  float scale = nuniq / 64.0f;

  float a = 0.f;
  for (int i = tid; i < 2048; i += 256) a += ws[WS_PART2 + i];
  float lr = 0.f;
  for (int i = tid; i < 1600; i += 256) lr += ws[WS_PART3L + i];
  float mr = 0.f;
  if (tid < 64) mr = ws[WS_PART3M + tid];

  float v = a / 32768.0f + scale * 0.05f * (lr + mr);
  v = wave_sum(v);
  __shared__ float red[4];
  if ((tid & 63) == 0) red[tid >> 6] = v;
  __syncthreads();
  if (tid == 0) out[0] = red[0] + red[1] + red[2] + red[3];
}

extern "C" void kernel_launch(void* const* d_in, const int* in_sizes, int n_in,
                              void* d_out, int out_size, void* d_ws, size_t ws_size,
                              hipStream_t stream) {
  const float* x       = (const float*)d_in[0];
  const float* mu_pop  = (const float*)d_in[1];
  const float* L_pop   = (const float*)d_in[2];
  const float* mu_subj = (const float*)d_in[3];
  const float* L_subj  = (const float*)d_in[4];
  const float* gamma   = (const float*)d_in[5];
  const int*   sids    = (const int*)d_in[6];
  float* out = (float*)d_out;
  float* ws  = (float*)d_ws;

  hipLaunchKernelGGL(k_prep, dim3(1664), dim3(256), 0, stream,
                     x, gamma, L_subj, mu_subj, sids, ws);
  hipLaunchKernelGGL(k_main, dim3(3712), dim3(256), 0, stream,
                     ws, L_subj, L_pop, mu_subj, mu_pop, sids, ws);
  hipLaunchKernelGGL(k4_final, dim3(1), dim3(256), 0, stream, sids, ws, out);
}

// Round 19
// 44.275 us; speedup vs baseline: 6.6521x; 1.0526x over previous
//
#include <hip/hip_runtime.h>
#include <hip/hip_bf16.h>
#include <math.h>

#define BB 32
#define TTOT 1024
#define KK 16
#define DD 80
#define PP 64

// workspace layout (float offsets)
#define WS_DCONST 128      // 512
#define WS_CVEC   1024     // 512*80 -> 41984
#define WS_PART2  41984    // 2048 -> 44032
#define WS_PART3L 44032    // 1600 -> 45632
#define WS_PART3M 45632    // 64 -> 45696
#define WS_GAMT   46080    // gamma^T fp32 [32][16][1024] -> 570368
#define WS_XBF16  570368   // X frag-major bf16 -> 2,143,232
#define WS_MINVB  2143232  // Minv frag-major bf16 -> 4,109,312 (16.4 MB)

typedef short bf16x8 __attribute__((ext_vector_type(8)));
typedef float f32x4 __attribute__((ext_vector_type(4)));

__device__ __forceinline__ float wave_sum(float v) {
#pragma unroll
  for (int o = 32; o > 0; o >>= 1) v += __shfl_down(v, o);
  return v;
}

__device__ __forceinline__ unsigned short f2bf(float f) {
  __hip_bfloat16 h = __float2bfloat16(f);
  return *reinterpret_cast<unsigned short*>(&h);
}

__device__ __forceinline__ bf16x8 pack8(float4 a, float4 b) {
  bf16x8 r;
  r[0] = (short)f2bf(a.x); r[1] = (short)f2bf(a.y);
  r[2] = (short)f2bf(a.z); r[3] = (short)f2bf(a.w);
  r[4] = (short)f2bf(b.x); r[5] = (short)f2bf(b.y);
  r[6] = (short)f2bf(b.z); r[7] = (short)f2bf(b.w);
  return r;
}

struct SmKx { float Lx[2][16][84]; };
struct SmKg { float tile[256][17]; };
struct SmK1 {
  float ys[DD * 81 + 64];
  float dinv[DD * 20];
  float Ls5[5][16][17];
  float lgd[DD];
  float rt[4][16 * 17];
};

// ---- PREP: k1_inv (0-511, heaviest, first) + kx_cast (512-1535) +
//            kg_t (1536-1663) + k3 reg (1664-3327).
// R18 insight: k3 depends only on raw inputs -> belongs in stage 1, where its
// HBM streaming hides under k1's MFMA recursion. k_main becomes pure k2.
__global__ __launch_bounds__(256, 1) void k_prep(const float* __restrict__ x,
                                                 const float* __restrict__ gamma,
                                                 const float* __restrict__ L_subj,
                                                 const float* __restrict__ L_pop,
                                                 const float* __restrict__ mu_subj,
                                                 const float* __restrict__ mu_pop,
                                                 const int* __restrict__ sids,
                                                 float* __restrict__ ws) {
  __shared__ union { SmKx kx; SmKg kg; SmK1 k1; } sm;
  __shared__ float red[4];
  const int bid = blockIdx.x;
  const int tid = threadIdx.x;

  if (bid < 512) {
    // ---- role K1: triangular inverse via MFMA block recursion
    const int k = bid & 15, b = bid >> 4;
    const int p = sids[b];
    const float* Lg = L_subj + ((size_t)(p * KK + k)) * DD * DD;
    const float* mug = mu_subj + (size_t)(p * KK + k) * DD;
    const int bk = b * KK + k;

    const int w = tid >> 6, l = tid & 63;
    const int lr = l & 15, lg = l >> 4;

    for (int i2 = tid; i2 < 5 * 256; i2 += 256) {
      int blk = i2 >> 8, ii = (i2 >> 4) & 15, mm = i2 & 15;
      sm.k1.Ls5[blk][ii][mm] = Lg[(blk * 16 + ii) * DD + blk * 16 + mm];
    }
    for (int i2 = tid; i2 < DD * 81 + 64; i2 += 256) sm.k1.ys[i2] = 0.f;
    __syncthreads();

    // Phase 1: invert diagonal 16x16 blocks from LDS (tid<80)
    if (tid < DD) {
      const int ci5 = tid >> 4, jj = tid & 15;
      float rd[16];
#pragma unroll
      for (int ii = 0; ii < 16; ++ii) rd[ii] = 1.0f / sm.k1.Ls5[ci5][ii][ii];
      float yc[16];
#pragma unroll
      for (int ii = 0; ii < 16; ++ii) {
        float v = (ii == jj) ? 1.0f : 0.0f;
#pragma unroll
        for (int mm = 0; mm < 16; ++mm)
          if (mm < ii) v = fmaf(-sm.k1.Ls5[ci5][ii][mm], yc[mm], v);
        yc[ii] = v * rd[ii];
      }
#pragma unroll
      for (int ii = 0; ii < 16; ++ii) sm.k1.dinv[(ci5 * 16 + ii) * 20 + jj] = yc[ii];
      sm.k1.lgd[tid] = logf(sm.k1.Ls5[ci5][jj][jj]);
    }
    __syncthreads();

    // Phase 2: 4-wave column ownership (w0:{0} w1:{1} w2:{2} w3:{3,4}),
    // lower-triangular tiles only, diagonal = Dinv copy. No barriers inside.
    float* rtw = sm.k1.rt[w];
    for (int nt = w; nt < 5; nt += (w == 3) ? 1 : 5) {
      const int col = nt * 16 + lr;
      if (lg == 0) {
#pragma unroll
        for (int ii = 0; ii < 16; ++ii)
          sm.k1.ys[(nt * 16 + ii) * 81 + col] = sm.k1.dinv[(nt * 16 + ii) * 20 + lr];
      }
      for (int ci = nt + 1; ci < 5; ++ci) {
        const int r0 = ci * 16;
        const int ktot = ci * 16;
        const int nch = (ci + 1) >> 1;

        bf16x8 aL0 = {}, aL1 = {};
        if (nch > 0 && (lg * 8) < ktot) {
          const float* src = &Lg[(r0 + lr) * DD + lg * 8];
          aL0 = pack8(*reinterpret_cast<const float4*>(src),
                      *reinterpret_cast<const float4*>(src + 4));
        }
        if (nch > 1 && (32 + lg * 8) < ktot) {
          const float* src = &Lg[(r0 + lr) * DD + 32 + lg * 8];
          aL1 = pack8(*reinterpret_cast<const float4*>(src),
                      *reinterpret_cast<const float4*>(src + 4));
        }
        bf16x8 aD = {};
        if (lg < 2) {
          const float* src = &sm.k1.dinv[(r0 + lr) * 20 + lg * 8];
          aD = pack8(*reinterpret_cast<const float4*>(src),
                     *reinterpret_cast<const float4*>(src + 4));
        }

        f32x4 S = {};
        if (nch > 0) {
          bf16x8 b0 = {};
          if ((lg * 8) < ktot) {
            const int kb = lg * 8;
#pragma unroll
            for (int jj = 0; jj < 8; ++jj)
              b0[jj] = (short)f2bf(sm.k1.ys[(kb + jj) * 81 + col]);
          }
          S = __builtin_amdgcn_mfma_f32_16x16x32_bf16(aL0, b0, S, 0, 0, 0);
        }
        if (nch > 1) {
          bf16x8 b1 = {};
          if ((32 + lg * 8) < ktot) {
            const int kb = 32 + lg * 8;
#pragma unroll
            for (int jj = 0; jj < 8; ++jj)
              b1[jj] = (short)f2bf(sm.k1.ys[(kb + jj) * 81 + col]);
          }
          S = __builtin_amdgcn_mfma_f32_16x16x32_bf16(aL1, b1, S, 0, 0, 0);
        }
#pragma unroll
        for (int r = 0; r < 4; ++r) rtw[(lg * 4 + r) * 17 + lr] = -S[r];
        bf16x8 bR = {};
        if (lg < 2) {
#pragma unroll
          for (int jj = 0; jj < 8; ++jj)
            bR[jj] = (short)f2bf(rtw[(lg * 8 + jj) * 17 + lr]);
        }
        f32x4 Y = {};
        Y = __builtin_amdgcn_mfma_f32_16x16x32_bf16(aD, bR, Y, 0, 0, 0);
#pragma unroll
        for (int r = 0; r < 4; ++r) sm.k1.ys[(r0 + lg * 4 + r) * 81 + col] = Y[r];
      }
    }
    __syncthreads();

    // Minv write in A-fragment-major layout (zeros in K-pad slots)
    __hip_bfloat16* Mf = (__hip_bfloat16*)(ws + WS_MINVB) + (size_t)bk * 7680;
    for (int s = tid; s < 960; s += 256) {
      int mtc = s >> 6, l2 = s & 63;
      int row = (mtc / 3) * 16 + (l2 & 15);
      int col0 = (mtc % 3) * 32 + (l2 >> 4) * 8;
      bf16x8 v = {};
      if (col0 < DD) {
#pragma unroll
        for (int jj = 0; jj < 8; ++jj) v[jj] = (short)f2bf(sm.k1.ys[row * 81 + col0 + jj]);
      }
      *reinterpret_cast<bf16x8*>(Mf + s * 8) = v;
    }

    if (tid < DD) {
      int i = tid;
      float ci = 0.f;
#pragma unroll 8
      for (int jj = 0; jj < DD; ++jj) ci = fmaf(sm.k1.ys[i * 81 + jj], mug[jj], ci);
      ws[WS_CVEC + bk * DD + i] = ci;
    }
    if (tid == 0) {
      float s = 0.f;
      for (int i = 0; i < DD; ++i) s += sm.k1.lgd[i];
      ws[WS_DCONST + bk] = (float)(0.5 * 80.0 * 1.8378770664093453) + s;
    }
    return;
  }

  if (bid < 1536) {
    // ---- role KX: x -> bf16 B-fragment-major; half-block per 16-t group
    const int h = tid >> 7, t = tid & 127;
    const int g = (bid - 512) * 2 + h;
    float(&Lx)[16][84] = sm.kx.Lx[h];
    const float* src = x + (size_t)g * 1280;
    for (int i2 = t; i2 < 320; i2 += 128) {
      float4 v = reinterpret_cast<const float4*>(src)[i2];
      int row = i2 / 20, c4 = (i2 % 20) * 4;
      *reinterpret_cast<float4*>(&Lx[row][c4]) = v;
    }
    __syncthreads();
    __hip_bfloat16* Xf = (__hip_bfloat16*)(ws + WS_XBF16) + (size_t)g * 1536;
    for (int s = t; s < 192; s += 128) {
      int c = s >> 6, l = s & 63, lg2 = (l >> 4), lr2 = l & 15;
      int col0 = c * 32 + lg2 * 8;
      bf16x8 v = {};
      if (col0 < DD) {
#pragma unroll
        for (int jj = 0; jj < 8; ++jj) v[jj] = (short)f2bf(Lx[lr2][col0 + jj]);
      }
      *reinterpret_cast<bf16x8*>(Xf + s * 8) = v;
    }
    return;
  }

  if (bid < 1664) {
    // ---- role KG: gamma [b][t][k] -> [b][k][t]
    const int idx0 = bid - 1536;
    const int tc = idx0 & 3, b = idx0 >> 2;
    const float* src = gamma + ((size_t)b * TTOT + tc * 256) * KK;
#pragma unroll
    for (int q = 0; q < 16; ++q) {
      int i2 = q * 256 + tid;
      sm.kg.tile[i2 >> 4][i2 & 15] = src[i2];
    }
    __syncthreads();
    float* dst = ws + WS_GAMT + (size_t)b * KK * TTOT;
#pragma unroll
    for (int q = 0; q < 16; ++q) {
      int i2 = q * 256 + tid;
      int kk = i2 >> 8, tl = i2 & 255;
      dst[kk * TTOT + tc * 256 + tl] = sm.kg.tile[tl][kk];
    }
    return;
  }

  // ---- role K3: L reg (chunk 0-24) + mu reg (chunk 25); inputs-only deps
  const int idx = bid - 1664;
  const int p = idx / 26, chunk = idx - p * 26;
  int found = 0;
  for (int b2 = 0; b2 < BB; ++b2) found |= (sids[b2] == p) ? 1 : 0;
  float* outp = (chunk < 25) ? &ws[WS_PART3L + p * 25 + chunk] : &ws[WS_PART3M + p];
  if (!found) {
    if (tid == 0) *outp = 0.f;
    return;
  }
  float s = 0.f;
  if (chunk < 25) {
    const float4* a4 = reinterpret_cast<const float4*>(L_subj) + (size_t)p * (KK * DD * DD / 4);
    const float4* b4 = reinterpret_cast<const float4*>(L_pop);
#pragma unroll
    for (int q = 0; q < 4; ++q) {
      int o = chunk * 1024 + q * 256 + tid;
      float4 a = a4[o], bb = b4[o];
      float d0 = a.x - bb.x, d1 = a.y - bb.y, d2 = a.z - bb.z, d3 = a.w - bb.w;
      s += d0 * d0 + d1 * d1 + d2 * d2 + d3 * d3;
    }
  } else {
    const float4* a4 = reinterpret_cast<const float4*>(mu_subj) + (size_t)p * (KK * DD / 4);
    const float4* b4 = reinterpret_cast<const float4*>(mu_pop);
    for (int o = tid; o < 320; o += 256) {
      float4 a = a4[o], bb = b4[o];
      float d0 = a.x - bb.x, d1 = a.y - bb.y, d2 = a.z - bb.z, d3 = a.w - bb.w;
      s += d0 * d0 + d1 * d1 + d2 * d2 + d3 * d3;
    }
  }
  s = wave_sum(s);
  if ((tid & 63) == 0) red[tid >> 6] = s;
  __syncthreads();
  if (tid == 0) *outp = red[0] + red[1] + red[2] + red[3];
}

// ---- MAIN: pure k2_mfma (2048 blocks) ----
__global__ __launch_bounds__(256) void k_main(const float* __restrict__ ws_ro,
                                              float* __restrict__ ws) {
  __shared__ float red[4];
  const int bid = blockIdx.x;
  const int tid = threadIdx.x;

  const int k = bid & 15, tt = (bid >> 4) & 3, b = bid >> 6;
  const int w = tid >> 6, l = tid & 63;
  const int lg = l >> 4, lr = l & 15;
  const int bk = b * KK + k;

  const __hip_bfloat16* Mf = (const __hip_bfloat16*)(ws_ro + WS_MINVB) + (size_t)bk * 7680;
  const __hip_bfloat16* Xf = (const __hip_bfloat16*)(ws_ro + WS_XBF16);
  const float* gamt = ws_ro + WS_GAMT + ((size_t)b * KK + k) * TTOT;
  const float* cc = ws_ro + WS_CVEC + bk * DD;
  const float dconst = ws_ro[WS_DCONST + bk];

  const int t0 = tt * 256 + w * 64;
  const int tg0 = tt * 16 + w * 4;

  f32x4 accf[5][4] = {};
#pragma unroll
  for (int c = 0; c < 3; ++c) {
    bf16x8 af[5], bf[4];
#pragma unroll
    for (int mt = 0; mt < 5; ++mt)
      af[mt] = *(const bf16x8*)(Mf + ((mt * 3 + c) * 64 + l) * 8);
#pragma unroll
    for (int nf = 0; nf < 4; ++nf)
      bf[nf] = *(const bf16x8*)(Xf + ((size_t)(b * 64 + tg0 + nf) * 192 + c * 64 + l) * 8);
#pragma unroll
    for (int mt = 0; mt < 5; ++mt)
#pragma unroll
      for (int nf = 0; nf < 4; ++nf)
        accf[mt][nf] = __builtin_amdgcn_mfma_f32_16x16x32_bf16(af[mt], bf[nf], accf[mt][nf], 0, 0, 0);
  }

  float c_r[5][4];
#pragma unroll
  for (int mt = 0; mt < 5; ++mt)
#pragma unroll
    for (int r = 0; r < 4; ++r)
      c_r[mt][r] = cc[mt * 16 + lg * 4 + r];

  float v = 0.f;
#pragma unroll
  for (int nf = 0; nf < 4; ++nf) {
    float s = 0.f;
#pragma unroll
    for (int mt = 0; mt < 5; ++mt)
#pragma unroll
      for (int r = 0; r < 4; ++r) {
        float z = accf[mt][nf][r] - c_r[mt][r];
        s = fmaf(z, z, s);
      }
    s += __shfl_xor(s, 16);
    s += __shfl_xor(s, 32);
    float g = 0.f;
    int t = t0 + nf * 16 + lr;
    if (l < 16) g = gamt[t];
    v = fmaf(g, dconst + 0.5f * s, v);
  }
  v = wave_sum(v);
  if (l == 0) red[w] = v;
  __syncthreads();
  if (tid == 0)
    ws[WS_PART2 + (b * 4 + tt) * KK + k] = red[0] + red[1] + red[2] + red[3];
}

// ---- K4: reduce all partials, compute n_unique, combine ----
__global__ __launch_bounds__(256) void k4_final(const int* __restrict__ sids,
                                                const float* __restrict__ ws,
                                                float* __restrict__ out) {
  int tid = threadIdx.x;
  __shared__ float nuniq;
  if (tid < 64) {
    int found = 0;
    for (int b2 = 0; b2 < BB; ++b2) found |= (sids[b2] == tid) ? 1 : 0;
    unsigned long long bal = __ballot(found != 0);
    if (tid == 0) nuniq = (float)__popcll(bal);
  }
  __syncthreads();
  float scale = nuniq / 64.0f;

  float a = 0.f;
  for (int i = tid; i < 2048; i += 256) a += ws[WS_PART2 + i];
  float lr = 0.f;
  for (int i = tid; i < 1600; i += 256) lr += ws[WS_PART3L + i];
  float mr = 0.f;
  if (tid < 64) mr = ws[WS_PART3M + tid];

  float v = a / 32768.0f + scale * 0.05f * (lr + mr);
  v = wave_sum(v);
  __shared__ float red[4];
  if ((tid & 63) == 0) red[tid >> 6] = v;
  __syncthreads();
  if (tid == 0) out[0] = red[0] + red[1] + red[2] + red[3];
}

extern "C" void kernel_launch(void* const* d_in, const int* in_sizes, int n_in,
                              void* d_out, int out_size, void* d_ws, size_t ws_size,
                              hipStream_t stream) {
  const float* x       = (const float*)d_in[0];
  const float* mu_pop  = (const float*)d_in[1];
  const float* L_pop   = (const float*)d_in[2];
  const float* mu_subj = (const float*)d_in[3];
  const float* L_subj  = (const float*)d_in[4];
  const float* gamma   = (const float*)d_in[5];
  const int*   sids    = (const int*)d_in[6];
  float* out = (float*)d_out;
  float* ws  = (float*)d_ws;

  hipLaunchKernelGGL(k_prep, dim3(3328), dim3(256), 0, stream,
                     x, gamma, L_subj, L_pop, mu_subj, mu_pop, sids, ws);
  hipLaunchKernelGGL(k_main, dim3(2048), dim3(256), 0, stream, ws, ws);
  hipLaunchKernelGGL(k4_final, dim3(1), dim3(256), 0, stream, sids, ws, out);
}

// Round 22
// 43.637 us; speedup vs baseline: 6.7494x; 1.0146x over previous
//
#include <hip/hip_runtime.h>
#include <hip/hip_bf16.h>
#include <math.h>

#define BB 32
#define TTOT 1024
#define KK 16
#define DD 80
#define PP 64

// workspace layout (float offsets)
#define WS_DCONST 128      // 512
#define WS_CVEC   1024     // 512*80 -> 41984
#define WS_PART2  41984    // 2048 -> 44032
#define WS_PART3L 44032    // 1600 -> 45632
#define WS_PART3M 45632    // 64 -> 45696
#define WS_GAMT   46080    // gamma^T fp32 [32][16][1024] -> 570368
#define WS_XBF16  570368   // X frag-major bf16 -> 2,143,232
#define WS_MINVB  2143232  // Minv frag-major bf16 -> 4,109,312 (16.4 MB)

typedef short bf16x8 __attribute__((ext_vector_type(8)));
typedef float f32x4 __attribute__((ext_vector_type(4)));

__device__ __forceinline__ float wave_sum(float v) {
#pragma unroll
  for (int o = 32; o > 0; o >>= 1) v += __shfl_down(v, o);
  return v;
}

__device__ __forceinline__ unsigned short f2bf(float f) {
  __hip_bfloat16 h = __float2bfloat16(f);
  return *reinterpret_cast<unsigned short*>(&h);
}

__device__ __forceinline__ bf16x8 pack8(float4 a, float4 b) {
  bf16x8 r;
  r[0] = (short)f2bf(a.x); r[1] = (short)f2bf(a.y);
  r[2] = (short)f2bf(a.z); r[3] = (short)f2bf(a.w);
  r[4] = (short)f2bf(b.x); r[5] = (short)f2bf(b.y);
  r[6] = (short)f2bf(b.z); r[7] = (short)f2bf(b.w);
  return r;
}

struct SmKx { float Lx[2][16][84]; };
struct SmKg { float tile[256][17]; };
struct SmK1 {
  float ys[DD * 81 + 64];
  float dinv[DD * 20];
  union {                       // Ls5: phase-1 only; rt: phase-2 only
    float Ls5[5][16][17];
    float rt[4][16 * 17];
  } u;
  float lgd[DD];                // written phase 1, read in epilogue
};
// SmK1 = 6544+1600+1360+80 = 9584 floats = 38.3 KB -> 4 blocks/CU (was 42.7KB/3)

// ---- PREP: k1_inv (0-511, heaviest, first) + kx_cast (512-1535) +
//            kg_t (1536-1663) + k3 reg (1664-3327).
__global__ __launch_bounds__(256, 1) void k_prep(const float* __restrict__ x,
                                                 const float* __restrict__ gamma,
                                                 const float* __restrict__ L_subj,
                                                 const float* __restrict__ L_pop,
                                                 const float* __restrict__ mu_subj,
                                                 const float* __restrict__ mu_pop,
                                                 const int* __restrict__ sids,
                                                 float* __restrict__ ws) {
  __shared__ union { SmKx kx; SmKg kg; SmK1 k1; } sm;
  __shared__ float red[4];
  const int bid = blockIdx.x;
  const int tid = threadIdx.x;

  if (bid < 512) {
    // ---- role K1: triangular inverse via MFMA block recursion
    const int k = bid & 15, b = bid >> 4;
    const int p = sids[b];
    const float* Lg = L_subj + ((size_t)(p * KK + k)) * DD * DD;
    const float* mug = mu_subj + (size_t)(p * KK + k) * DD;
    const int bk = b * KK + k;

    const int w = tid >> 6, l = tid & 63;
    const int lr = l & 15, lg = l >> 4;

    for (int i2 = tid; i2 < 5 * 256; i2 += 256) {
      int blk = i2 >> 8, ii = (i2 >> 4) & 15, mm = i2 & 15;
      sm.k1.u.Ls5[blk][ii][mm] = Lg[(blk * 16 + ii) * DD + blk * 16 + mm];
    }
    for (int i2 = tid; i2 < DD * 81 + 64; i2 += 256) sm.k1.ys[i2] = 0.f;
    __syncthreads();

    // Phase 1: invert diagonal 16x16 blocks from LDS (tid<80)
    if (tid < DD) {
      const int ci5 = tid >> 4, jj = tid & 15;
      float rd[16];
#pragma unroll
      for (int ii = 0; ii < 16; ++ii) rd[ii] = 1.0f / sm.k1.u.Ls5[ci5][ii][ii];
      float yc[16];
#pragma unroll
      for (int ii = 0; ii < 16; ++ii) {
        float v = (ii == jj) ? 1.0f : 0.0f;
#pragma unroll
        for (int mm = 0; mm < 16; ++mm)
          if (mm < ii) v = fmaf(-sm.k1.u.Ls5[ci5][ii][mm], yc[mm], v);
        yc[ii] = v * rd[ii];
      }
#pragma unroll
      for (int ii = 0; ii < 16; ++ii) sm.k1.dinv[(ci5 * 16 + ii) * 20 + jj] = yc[ii];
      sm.k1.lgd[tid] = logf(sm.k1.u.Ls5[ci5][jj][jj]);
    }
    __syncthreads();   // after this barrier Ls5 is dead; rt aliases it

    // Phase 2: 4-wave column ownership (w0:{0} w1:{1} w2:{2} w3:{3,4}),
    // lower-triangular tiles only, diagonal = Dinv copy. No barriers inside.
    float* rtw = sm.k1.u.rt[w];
    for (int nt = w; nt < 5; nt += (w == 3) ? 1 : 5) {
      const int col = nt * 16 + lr;
      if (lg == 0) {
#pragma unroll
        for (int ii = 0; ii < 16; ++ii)
          sm.k1.ys[(nt * 16 + ii) * 81 + col] = sm.k1.dinv[(nt * 16 + ii) * 20 + lr];
      }
      for (int ci = nt + 1; ci < 5; ++ci) {
        const int r0 = ci * 16;
        const int ktot = ci * 16;
        const int nch = (ci + 1) >> 1;

        bf16x8 aL0 = {}, aL1 = {};
        if (nch > 0 && (lg * 8) < ktot) {
          const float* src = &Lg[(r0 + lr) * DD + lg * 8];
          aL0 = pack8(*reinterpret_cast<const float4*>(src),
                      *reinterpret_cast<const float4*>(src + 4));
        }
        if (nch > 1 && (32 + lg * 8) < ktot) {
          const float* src = &Lg[(r0 + lr) * DD + 32 + lg * 8];
          aL1 = pack8(*reinterpret_cast<const float4*>(src),
                      *reinterpret_cast<const float4*>(src + 4));
        }
        bf16x8 aD = {};
        if (lg < 2) {
          const float* src = &sm.k1.dinv[(r0 + lr) * 20 + lg * 8];
          aD = pack8(*reinterpret_cast<const float4*>(src),
                     *reinterpret_cast<const float4*>(src + 4));
        }

        f32x4 S = {};
        if (nch > 0) {
          bf16x8 b0 = {};
          if ((lg * 8) < ktot) {
            const int kb = lg * 8;
#pragma unroll
            for (int jj = 0; jj < 8; ++jj)
              b0[jj] = (short)f2bf(sm.k1.ys[(kb + jj) * 81 + col]);
          }
          S = __builtin_amdgcn_mfma_f32_16x16x32_bf16(aL0, b0, S, 0, 0, 0);
        }
        if (nch > 1) {
          bf16x8 b1 = {};
          if ((32 + lg * 8) < ktot) {
            const int kb = 32 + lg * 8;
#pragma unroll
            for (int jj = 0; jj < 8; ++jj)
              b1[jj] = (short)f2bf(sm.k1.ys[(kb + jj) * 81 + col]);
          }
          S = __builtin_amdgcn_mfma_f32_16x16x32_bf16(aL1, b1, S, 0, 0, 0);
        }
#pragma unroll
        for (int r = 0; r < 4; ++r) rtw[(lg * 4 + r) * 17 + lr] = -S[r];
        bf16x8 bR = {};
        if (lg < 2) {
#pragma unroll
          for (int jj = 0; jj < 8; ++jj)
            bR[jj] = (short)f2bf(rtw[(lg * 8 + jj) * 17 + lr]);
        }
        f32x4 Y = {};
        Y = __builtin_amdgcn_mfma_f32_16x16x32_bf16(aD, bR, Y, 0, 0, 0);
#pragma unroll
        for (int r = 0; r < 4; ++r) sm.k1.ys[(r0 + lg * 4 + r) * 81 + col] = Y[r];
      }
    }
    __syncthreads();

    // Minv write in A-fragment-major layout (zeros in K-pad slots)
    __hip_bfloat16* Mf = (__hip_bfloat16*)(ws + WS_MINVB) + (size_t)bk * 7680;
    for (int s = tid; s < 960; s += 256) {
      int mtc = s >> 6, l2 = s & 63;
      int row = (mtc / 3) * 16 + (l2 & 15);
      int col0 = (mtc % 3) * 32 + (l2 >> 4) * 8;
      bf16x8 v = {};
      if (col0 < DD) {
#pragma unroll
        for (int jj = 0; jj < 8; ++jj) v[jj] = (short)f2bf(sm.k1.ys[row * 81 + col0 + jj]);
      }
      *reinterpret_cast<bf16x8*>(Mf + s * 8) = v;
    }

    if (tid < DD) {
      int i = tid;
      float ci = 0.f;
#pragma unroll 8
      for (int jj = 0; jj < DD; ++jj) ci = fmaf(sm.k1.ys[i * 81 + jj], mug[jj], ci);
      ws[WS_CVEC + bk * DD + i] = ci;
    }
    if (tid == 0) {
      float s = 0.f;
      for (int i = 0; i < DD; ++i) s += sm.k1.lgd[i];
      ws[WS_DCONST + bk] = (float)(0.5 * 80.0 * 1.8378770664093453) + s;
    }
    return;
  }

  if (bid < 1536) {
    // ---- role KX: x -> bf16 B-fragment-major; half-block per 16-t group
    const int h = tid >> 7, t = tid & 127;
    const int g = (bid - 512) * 2 + h;
    float(&Lx)[16][84] = sm.kx.Lx[h];
    const float* src = x + (size_t)g * 1280;
    for (int i2 = t; i2 < 320; i2 += 128) {
      float4 v = reinterpret_cast<const float4*>(src)[i2];
      int row = i2 / 20, c4 = (i2 % 20) * 4;
      *reinterpret_cast<float4*>(&Lx[row][c4]) = v;
    }
    __syncthreads();
    __hip_bfloat16* Xf = (__hip_bfloat16*)(ws + WS_XBF16) + (size_t)g * 1536;
    for (int s = t; s < 192; s += 128) {
      int c = s >> 6, l = s & 63, lg2 = (l >> 4), lr2 = l & 15;
      int col0 = c * 32 + lg2 * 8;
      bf16x8 v = {};
      if (col0 < DD) {
#pragma unroll
        for (int jj = 0; jj < 8; ++jj) v[jj] = (short)f2bf(Lx[lr2][col0 + jj]);
      }
      *reinterpret_cast<bf16x8*>(Xf + s * 8) = v;
    }
    return;
  }

  if (bid < 1664) {
    // ---- role KG: gamma [b][t][k] -> [b][k][t]
    const int idx0 = bid - 1536;
    const int tc = idx0 & 3, b = idx0 >> 2;
    const float* src = gamma + ((size_t)b * TTOT + tc * 256) * KK;
#pragma unroll
    for (int q = 0; q < 16; ++q) {
      int i2 = q * 256 + tid;
      sm.kg.tile[i2 >> 4][i2 & 15] = src[i2];
    }
    __syncthreads();
    float* dst = ws + WS_GAMT + (size_t)b * KK * TTOT;
#pragma unroll
    for (int q = 0; q < 16; ++q) {
      int i2 = q * 256 + tid;
      int kk = i2 >> 8, tl = i2 & 255;
      dst[kk * TTOT + tc * 256 + tl] = sm.kg.tile[tl][kk];
    }
    return;
  }

  // ---- role K3: L reg (chunk 0-24) + mu reg (chunk 25); inputs-only deps
  const int idx = bid - 1664;
  const int p = idx / 26, chunk = idx - p * 26;
  int found = 0;
  for (int b2 = 0; b2 < BB; ++b2) found |= (sids[b2] == p) ? 1 : 0;
  float* outp = (chunk < 25) ? &ws[WS_PART3L + p * 25 + chunk] : &ws[WS_PART3M + p];
  if (!found) {
    if (tid == 0) *outp = 0.f;
    return;
  }
  float s = 0.f;
  if (chunk < 25) {
    const float4* a4 = reinterpret_cast<const float4*>(L_subj) + (size_t)p * (KK * DD * DD / 4);
    const float4* b4 = reinterpret_cast<const float4*>(L_pop);
#pragma unroll
    for (int q = 0; q < 4; ++q) {
      int o = chunk * 1024 + q * 256 + tid;
      float4 a = a4[o], bb = b4[o];
      float d0 = a.x - bb.x, d1 = a.y - bb.y, d2 = a.z - bb.z, d3 = a.w - bb.w;
      s += d0 * d0 + d1 * d1 + d2 * d2 + d3 * d3;
    }
  } else {
    const float4* a4 = reinterpret_cast<const float4*>(mu_subj) + (size_t)p * (KK * DD / 4);
    const float4* b4 = reinterpret_cast<const float4*>(mu_pop);
    for (int o = tid; o < 320; o += 256) {
      float4 a = a4[o], bb = b4[o];
      float d0 = a.x - bb.x, d1 = a.y - bb.y, d2 = a.z - bb.z, d3 = a.w - bb.w;
      s += d0 * d0 + d1 * d1 + d2 * d2 + d3 * d3;
    }
  }
  s = wave_sum(s);
  if ((tid & 63) == 0) red[tid >> 6] = s;
  __syncthreads();
  if (tid == 0) *outp = red[0] + red[1] + red[2] + red[3];
}

// ---- MAIN: pure k2_mfma; 1024 blocks, 2 ttiles serial per block ----
// Second ttile's Minv fragment loads hit L1/L2 (same bk) -> per-(b,k)
// Minv traffic halves; accumulators reused after each epilogue.
__global__ __launch_bounds__(256) void k_main(const float* __restrict__ ws_ro,
                                              float* __restrict__ ws) {
  __shared__ float red[4];
  const int bid = blockIdx.x;
  const int tid = threadIdx.x;

  const int k = bid & 15, tp = (bid >> 4) & 1, b = bid >> 5;
  const int w = tid >> 6, l = tid & 63;
  const int lg = l >> 4, lr = l & 15;
  const int bk = b * KK + k;

  const __hip_bfloat16* Mf = (const __hip_bfloat16*)(ws_ro + WS_MINVB) + (size_t)bk * 7680;
  const __hip_bfloat16* Xf = (const __hip_bfloat16*)(ws_ro + WS_XBF16);
  const float* gamt = ws_ro + WS_GAMT + ((size_t)b * KK + k) * TTOT;
  const float* cc = ws_ro + WS_CVEC + bk * DD;
  const float dconst = ws_ro[WS_DCONST + bk];

  float c_r[5][4];
#pragma unroll
  for (int mt = 0; mt < 5; ++mt)
#pragma unroll
    for (int r = 0; r < 4; ++r)
      c_r[mt][r] = cc[mt * 16 + lg * 4 + r];

#pragma unroll
  for (int it = 0; it < 2; ++it) {
    const int tt = tp * 2 + it;
    const int t0 = tt * 256 + w * 64;
    const int tg0 = tt * 16 + w * 4;

    f32x4 accf[5][4] = {};
#pragma unroll
    for (int c = 0; c < 3; ++c) {
      bf16x8 af[5], bf[4];
#pragma unroll
      for (int mt = 0; mt < 5; ++mt)
        af[mt] = *(const bf16x8*)(Mf + ((mt * 3 + c) * 64 + l) * 8);
#pragma unroll
      for (int nf = 0; nf < 4; ++nf)
        bf[nf] = *(const bf16x8*)(Xf + ((size_t)(b * 64 + tg0 + nf) * 192 + c * 64 + l) * 8);
#pragma unroll
      for (int mt = 0; mt < 5; ++mt)
#pragma unroll
        for (int nf = 0; nf < 4; ++nf)
          accf[mt][nf] = __builtin_amdgcn_mfma_f32_16x16x32_bf16(af[mt], bf[nf], accf[mt][nf], 0, 0, 0);
    }

    float v = 0.f;
#pragma unroll
    for (int nf = 0; nf < 4; ++nf) {
      float s = 0.f;
#pragma unroll
      for (int mt = 0; mt < 5; ++mt)
#pragma unroll
        for (int r = 0; r < 4; ++r) {
          float z = accf[mt][nf][r] - c_r[mt][r];
          s = fmaf(z, z, s);
        }
      s += __shfl_xor(s, 16);
      s += __shfl_xor(s, 32);
      float g = 0.f;
      int t = t0 + nf * 16 + lr;
      if (l < 16) g = gamt[t];
      v = fmaf(g, dconst + 0.5f * s, v);
    }
    v = wave_sum(v);
    if (l == 0) red[w] = v;
    __syncthreads();
    if (tid == 0)
      ws[WS_PART2 + (b * 4 + tt) * KK + k] = red[0] + red[1] + red[2] + red[3];
    __syncthreads();  // protect red[] before next iteration overwrites
  }
}

// ---- K4: reduce all partials, compute n_unique, combine ----
__global__ __launch_bounds__(256) void k4_final(const int* __restrict__ sids,
                                                const float* __restrict__ ws,
                                                float* __restrict__ out) {
  int tid = threadIdx.x;
  __shared__ float nuniq;
  if (tid < 64) {
    int found = 0;
    for (int b2 = 0; b2 < BB; ++b2) found |= (sids[b2] == tid) ? 1 : 0;
    unsigned long long bal = __ballot(found != 0);
    if (tid == 0) nuniq = (float)__popcll(bal);
  }
  __syncthreads();
  float scale = nuniq / 64.0f;

  float a = 0.f;
  for (int i = tid; i < 2048; i += 256) a += ws[WS_PART2 + i];
  float lr = 0.f;
  for (int i = tid; i < 1600; i += 256) lr += ws[WS_PART3L + i];
  float mr = 0.f;
  if (tid < 64) mr = ws[WS_PART3M + tid];

  float v = a / 32768.0f + scale * 0.05f * (lr + mr);
  v = wave_sum(v);
  __shared__ float red[4];
  if ((tid & 63) == 0) red[tid >> 6] = v;
  __syncthreads();
  if (tid == 0) out[0] = red[0] + red[1] + red[2] + red[3];
}

extern "C" void kernel_launch(void* const* d_in, const int* in_sizes, int n_in,
                              void* d_out, int out_size, void* d_ws, size_t ws_size,
                              hipStream_t stream) {
  const float* x       = (const float*)d_in[0];
  const float* mu_pop  = (const float*)d_in[1];
  const float* L_pop   = (const float*)d_in[2];
  const float* mu_subj = (const float*)d_in[3];
  const float* L_subj  = (const float*)d_in[4];
  const float* gamma   = (const float*)d_in[5];
  const int*   sids    = (const int*)d_in[6];
  float* out = (float*)d_out;
  float* ws  = (float*)d_ws;

  hipLaunchKernelGGL(k_prep, dim3(3328), dim3(256), 0, stream,
                     x, gamma, L_subj, L_pop, mu_subj, mu_pop, sids, ws);
  hipLaunchKernelGGL(k_main, dim3(1024), dim3(256), 0, stream, ws, ws);
  hipLaunchKernelGGL(k4_final, dim3(1), dim3(256), 0, stream, sids, ws, out);
}